// Round 2
// 2875.505 us; speedup vs baseline: 4.0805x; 4.0805x over previous
//
#include <hip/hip_runtime.h>

// GPT forward on MI355X. R5 = R4 resubmit (container infra flake, no counters).
// R4: replaced serial-shuffle attention (MfmaUtil=0, 1660us/layer = 85% of
// runtime) with MFMA flash attention.
// Internal format fixed: fp32 residual h, bf16 MFMA operands. d_out dtype per flag.

typedef unsigned short ushort_t;
typedef unsigned int uint_t;
typedef __bf16 bf16x8 __attribute__((ext_vector_type(8)));
typedef float floatx4 __attribute__((ext_vector_type(4)));

#define D_ 768
#define T_ 2048
#define H_ 12
#define L_ 6
#define F_ 3072
#define V_ 32000

__device__ __forceinline__ float b2f(ushort_t u) {
    union { uint_t i; float f; } v; v.i = ((uint_t)u) << 16; return v.f;
}
__device__ __forceinline__ ushort_t f2b(float f) {
    uint_t x = __builtin_bit_cast(uint_t, f);
    uint_t r = (x + 0x7fffu + ((x >> 16) & 1u)) >> 16;
    return (ushort_t)r;
}
__device__ __forceinline__ float ldf(const void* p, size_t idx, int isbf) {
    return isbf ? b2f(((const ushort_t*)p)[idx]) : ((const float*)p)[idx];
}
__device__ __forceinline__ float wave_sum(float v) {
    for (int o = 32; o; o >>= 1) v += __shfl_xor(v, o);
    return v;
}
__device__ __forceinline__ float wave_max(float v) {
    for (int o = 32; o; o >>= 1) v = fmaxf(v, __shfl_xor(v, o));
    return v;
}

__global__ void sniff_kernel(const void* __restrict__ pos, int* __restrict__ flag) {
    if (threadIdx.x == 0 && blockIdx.x == 0) {
        const uint_t* w = (const uint_t*)pos;
        int c = 0;
        for (int i = 0; i < 64; ++i) {
            uint_t lo = w[i] & 0xffffu;
            int e = (int)((lo >> 7) & 0xff);
            if (e >= 110 && e < 127) ++c;
        }
        *flag = (c >= 32) ? 1 : 0;  // 1 = bf16 storage
    }
}

__global__ __launch_bounds__(256) void embed_kernel(
    const int* __restrict__ x, const void* __restrict__ tok,
    const void* __restrict__ pos, float* __restrict__ h,
    const int* __restrict__ flagp) {
    const int isbf = *flagp;
    int t = blockIdx.x, tid = threadIdx.x;
    int id = x[t];
    float* hr = h + (size_t)t * D_;
#pragma unroll
    for (int e = 0; e < 3; ++e) {
        int d = tid + e * 256;
        hr[d] = ldf(tok, (size_t)id * D_ + d, isbf) +
                ldf(pos, (size_t)t * D_ + d, isbf);
    }
}

__global__ __launch_bounds__(256) void ln_kernel(
    const float* __restrict__ x, const void* __restrict__ g, size_t go,
    const void* __restrict__ b, size_t bo, ushort_t* __restrict__ out,
    const int* __restrict__ flagp) {
    const int isbf = *flagp;
    int row = blockIdx.x, tid = threadIdx.x;
    int lane = tid & 63, wid = tid >> 6;
    const float* xr = x + (size_t)row * D_;
    float v0 = xr[tid], v1 = xr[tid + 256], v2 = xr[tid + 512];
    __shared__ float s1[4], s2[4];
    float s = wave_sum(v0 + v1 + v2);
    if (!lane) s1[wid] = s;
    __syncthreads();
    float mean = (s1[0] + s1[1] + s1[2] + s1[3]) * (1.f / 768.f);
    float d0 = v0 - mean, d1 = v1 - mean, d2 = v2 - mean;
    float q = wave_sum(d0 * d0 + d1 * d1 + d2 * d2);
    if (!lane) s2[wid] = q;
    __syncthreads();
    float var = (s2[0] + s2[1] + s2[2] + s2[3]) * (1.f / 768.f);
    float rstd = rsqrtf(var + 1e-5f);
    ushort_t* orow = out + (size_t)row * D_;
    orow[tid] = f2b(d0 * rstd * ldf(g, go + tid, isbf) + ldf(b, bo + tid, isbf));
    orow[tid + 256] = f2b(d1 * rstd * ldf(g, go + tid + 256, isbf) + ldf(b, bo + tid + 256, isbf));
    orow[tid + 512] = f2b(d2 * rstd * ldf(g, go + tid + 512, isbf) + ldf(b, bo + tid + 512, isbf));
}

// C[M,N] = A[M,K] * B[N,K]^T.  A: internal bf16. B/bias: flag dtype.
// EPI 0: bf16 store  1: +bias,GELU,bf16 store  2: resid+=  3: resid+=+bias
// EPI 4: store to d_out (dtype per flag)
template <int EPI>
__global__ __launch_bounds__(256) void gemm_bt(
    const ushort_t* __restrict__ A, const void* __restrict__ B, size_t Bo,
    const void* __restrict__ bias, size_t biaso, ushort_t* __restrict__ obf,
    float* __restrict__ resid, int M, int N, int K,
    const int* __restrict__ flagp) {
    const int isbf = *flagp;
    __shared__ ushort_t lds[8192];
    const int tid = threadIdx.x;
    const int lane = tid & 63;
    const int wid = tid >> 6;
    const int wm = wid >> 1, wn = wid & 1;
    const int m0 = blockIdx.y * 128, n0 = blockIdx.x * 128;
    const int lm = lane & 15, lq = lane >> 4;

    floatx4 acc[4][4] = {};

    const int arow = tid >> 2, aseg = tid & 3;
    const ushort_t* gA = A + (size_t)(m0 + arow) * K + aseg * 8;
    const size_t bofs = Bo + (size_t)(n0 + arow) * K + aseg * 8;
    const ushort_t* gBh = (const ushort_t*)B + bofs;
    const float* gBf = (const float*)B + bofs;
    ushort_t* sA = lds;
    ushort_t* sB = lds + 4096;

    for (int k0 = 0; k0 < K; k0 += 32) {
        *(uint4*)(sA + tid * 8) = *(const uint4*)(gA + k0);
        *(uint4*)(sA + 2048 + tid * 8) = *(const uint4*)(gA + (size_t)64 * K + k0);
        if (isbf) {
            *(uint4*)(sB + tid * 8) = *(const uint4*)(gBh + k0);
            *(uint4*)(sB + 2048 + tid * 8) = *(const uint4*)(gBh + (size_t)64 * K + k0);
        } else {
            union { ushort_t u[8]; uint4 v; } p0, p1;
            float4 x0 = *(const float4*)(gBf + k0);
            float4 x1 = *(const float4*)(gBf + k0 + 4);
            float4 y0 = *(const float4*)(gBf + (size_t)64 * K + k0);
            float4 y1 = *(const float4*)(gBf + (size_t)64 * K + k0 + 4);
            p0.u[0] = f2b(x0.x); p0.u[1] = f2b(x0.y); p0.u[2] = f2b(x0.z); p0.u[3] = f2b(x0.w);
            p0.u[4] = f2b(x1.x); p0.u[5] = f2b(x1.y); p0.u[6] = f2b(x1.z); p0.u[7] = f2b(x1.w);
            p1.u[0] = f2b(y0.x); p1.u[1] = f2b(y0.y); p1.u[2] = f2b(y0.z); p1.u[3] = f2b(y0.w);
            p1.u[4] = f2b(y1.x); p1.u[5] = f2b(y1.y); p1.u[6] = f2b(y1.z); p1.u[7] = f2b(y1.w);
            *(uint4*)(sB + tid * 8) = p0.v;
            *(uint4*)(sB + 2048 + tid * 8) = p1.v;
        }
        __syncthreads();
        bf16x8 af[4], bfr[4];
#pragma unroll
        for (int f = 0; f < 4; ++f) {
            af[f] = *(const bf16x8*)(sA + (wm * 64 + f * 16 + lm) * 32 + lq * 8);
            bfr[f] = *(const bf16x8*)(sB + (wn * 64 + f * 16 + lm) * 32 + lq * 8);
        }
#pragma unroll
        for (int i = 0; i < 4; ++i)
#pragma unroll
            for (int j = 0; j < 4; ++j)
                acc[i][j] = __builtin_amdgcn_mfma_f32_16x16x32_bf16(
                    af[i], bfr[j], acc[i][j], 0, 0, 0);
        __syncthreads();
    }

#pragma unroll
    for (int i = 0; i < 4; ++i) {
#pragma unroll
        for (int j = 0; j < 4; ++j) {
#pragma unroll
            for (int r = 0; r < 4; ++r) {
                int row = m0 + wm * 64 + i * 16 + lq * 4 + r;
                int col = n0 + wn * 64 + j * 16 + lm;
                float c = acc[i][j][r];
                if (EPI == 1 || EPI == 3) c += ldf(bias, biaso + col, isbf);
                if (EPI == 1) c = 0.5f * c * (1.f + erff(c * 0.70710678118f));
                size_t idx = (size_t)row * N + col;
                if (EPI == 0 || EPI == 1) {
                    obf[idx] = f2b(c);
                } else if (EPI == 4) {
                    if (isbf) obf[idx] = f2b(c);
                    else ((float*)obf)[idx] = c;
                } else {
                    resid[idx] += c;
                }
            }
        }
    }
}

// MFMA flash attention. Grid (T/64, H), 256 threads = 4 waves.
// Block handles 64 query rows of one head; wave w owns rows w*16..w*16+15.
// qkv layout: [T][3D], Q at h*64, K at D+h*64, V at 2D+h*64 (bf16).
__global__ __launch_bounds__(256) void attn_mfma(
    const ushort_t* __restrict__ qkv, ushort_t* __restrict__ ctx) {
    // K tile row-major [k][d], stride 72 (+8 pad -> 2-way bank = free on b128 reads)
    __shared__ __attribute__((aligned(16))) ushort_t sK[64 * 72];
    // V^T tile [d][k], stride 72
    __shared__ __attribute__((aligned(16))) ushort_t sVT[64 * 72];
    // P scratch, 16 rows x 72 per wave
    __shared__ __attribute__((aligned(16))) ushort_t sP[64 * 72];

    const int tid = threadIdx.x;
    const int lane = tid & 63;
    const int w = tid >> 6;
    const int lm = lane & 15, lq = lane >> 4;
    const int qt = (int)gridDim.x - 1 - (int)blockIdx.x;  // heavy tiles first
    const int q0 = qt * 64;
    const int h = blockIdx.y;

    // Q fragments (A-operand), pre-scaled by 1/sqrt(64)=0.125 (exact in bf16)
    bf16x8 qf[2];
    {
        const int qrow = q0 + w * 16 + lm;
        const ushort_t* src = qkv + (size_t)qrow * (3 * D_) + h * 64 + lq * 8;
#pragma unroll
        for (int kk = 0; kk < 2; ++kk) {
            union { ushort_t u[8]; uint4 v; bf16x8 b; } tmp;
            tmp.v = *(const uint4*)(src + kk * 32);
#pragma unroll
            for (int e = 0; e < 8; ++e) tmp.u[e] = f2b(b2f(tmp.u[e]) * 0.125f);
            qf[kk] = tmp.b;
        }
    }

    floatx4 acc_o[4] = {};
    float m[4], l[4];
#pragma unroll
    for (int r = 0; r < 4; ++r) { m[r] = -1e30f; l[r] = 0.f; }

    const int krow_s = tid >> 3;  // 0..31
    const int seg = tid & 7;
    ushort_t* pw = sP + w * (16 * 72);

    for (int j0 = 0; j0 <= q0; j0 += 64) {
        // --- stage K tile and V^T tile (reg-staged, all 256 threads) ---
#pragma unroll
        for (int p = 0; p < 2; ++p) {
            const int kr = p * 32 + krow_s;
            const size_t rb = (size_t)(j0 + kr) * (3 * D_) + h * 64 + seg * 8;
            *(uint4*)(sK + kr * 72 + seg * 8) = *(const uint4*)(qkv + rb + D_);
            union { ushort_t u[8]; uint4 v; } tv;
            tv.v = *(const uint4*)(qkv + rb + 2 * D_);
#pragma unroll
            for (int e = 0; e < 8; ++e) sVT[(seg * 8 + e) * 72 + kr] = tv.u[e];
        }
        __syncthreads();

        // --- S = Q K^T (16x64 per wave) ---
        floatx4 sa[4] = {};
#pragma unroll
        for (int nf = 0; nf < 4; ++nf) {
#pragma unroll
            for (int kk = 0; kk < 2; ++kk) {
                bf16x8 kf = *(const bf16x8*)(sK + (nf * 16 + lm) * 72 + kk * 32 + lq * 8);
                sa[nf] = __builtin_amdgcn_mfma_f32_16x16x32_bf16(qf[kk], kf, sa[nf], 0, 0, 0);
            }
        }
        if (j0 == q0) {  // diagonal tile: causal mask (uniform branch)
#pragma unroll
            for (int nf = 0; nf < 4; ++nf)
#pragma unroll
                for (int r = 0; r < 4; ++r)
                    if (j0 + nf * 16 + lm > q0 + w * 16 + lq * 4 + r) sa[nf][r] = -1e30f;
        }

        // --- online softmax: reduce over k (16-lane group, all lanes active) ---
        float rmax[4];
#pragma unroll
        for (int r = 0; r < 4; ++r)
            rmax[r] = fmaxf(fmaxf(sa[0][r], sa[1][r]), fmaxf(sa[2][r], sa[3][r]));
#pragma unroll
        for (int r = 0; r < 4; ++r) {
            rmax[r] = fmaxf(rmax[r], __shfl_xor(rmax[r], 1));
            rmax[r] = fmaxf(rmax[r], __shfl_xor(rmax[r], 2));
            rmax[r] = fmaxf(rmax[r], __shfl_xor(rmax[r], 4));
            rmax[r] = fmaxf(rmax[r], __shfl_xor(rmax[r], 8));
        }
        float alpha[4], rsum[4];
#pragma unroll
        for (int r = 0; r < 4; ++r) {
            float mn = fmaxf(m[r], rmax[r]);
            alpha[r] = __expf(m[r] - mn);
            m[r] = mn;
            rsum[r] = 0.f;
        }
#pragma unroll
        for (int nf = 0; nf < 4; ++nf)
#pragma unroll
            for (int r = 0; r < 4; ++r) {
                float pe = __expf(sa[nf][r] - m[r]);
                rsum[r] += pe;
                pw[(lq * 4 + r) * 72 + nf * 16 + lm] = f2b(pe);
            }
#pragma unroll
        for (int r = 0; r < 4; ++r) {
            rsum[r] += __shfl_xor(rsum[r], 1);
            rsum[r] += __shfl_xor(rsum[r], 2);
            rsum[r] += __shfl_xor(rsum[r], 4);
            rsum[r] += __shfl_xor(rsum[r], 8);
            l[r] = l[r] * alpha[r] + rsum[r];
        }
#pragma unroll
        for (int nf = 0; nf < 4; ++nf)
#pragma unroll
            for (int r = 0; r < 4; ++r) acc_o[nf][r] *= alpha[r];

        // --- O += P V (P re-fragmented via per-wave LDS patch) ---
        bf16x8 pa[2];
#pragma unroll
        for (int kk = 0; kk < 2; ++kk)
            pa[kk] = *(const bf16x8*)(pw + lm * 72 + kk * 32 + lq * 8);
#pragma unroll
        for (int nf = 0; nf < 4; ++nf) {
#pragma unroll
            for (int kk = 0; kk < 2; ++kk) {
                bf16x8 vf = *(const bf16x8*)(sVT + (nf * 16 + lm) * 72 + kk * 32 + lq * 8);
                acc_o[nf] = __builtin_amdgcn_mfma_f32_16x16x32_bf16(pa[kk], vf, acc_o[nf], 0, 0, 0);
            }
        }
        __syncthreads();  // protect sK/sVT before next tile's staging
    }

    float inv[4];
#pragma unroll
    for (int r = 0; r < 4; ++r) inv[r] = 1.f / fmaxf(l[r], 1e-30f);
#pragma unroll
    for (int nf = 0; nf < 4; ++nf)
#pragma unroll
        for (int r = 0; r < 4; ++r) {
            int q = q0 + w * 16 + lq * 4 + r;
            ctx[(size_t)q * D_ + h * 64 + nf * 16 + lm] = f2b(acc_o[nf][r] * inv[r]);
        }
}

__global__ __launch_bounds__(256) void loss_rows(
    const void* __restrict__ logits, const int* __restrict__ tg,
    float* __restrict__ rowacc, const int* __restrict__ flagp) {
    const int isbf = *flagp;
    int t = blockIdx.x, tid = threadIdx.x;
    int lane = tid & 63, wid = tid >> 6;
    const ushort_t* lrh = (const ushort_t*)logits + (size_t)t * V_;
    const float* lrf = (const float*)logits + (size_t)t * V_;
    __shared__ float sm[4], ss[4];
    float mx = -1e30f;
    for (int j = tid; j < V_ / 8; j += 256) {
        float v[8];
        if (isbf) {
            uint4 u = ((const uint4*)lrh)[j];
            uint_t w[4] = {u.x, u.y, u.z, u.w};
#pragma unroll
            for (int p = 0; p < 4; ++p) {
                v[p * 2] = b2f((ushort_t)(w[p] & 0xffff));
                v[p * 2 + 1] = b2f((ushort_t)(w[p] >> 16));
            }
        } else {
            float4 a = ((const float4*)lrf)[j * 2];
            float4 bq = ((const float4*)lrf)[j * 2 + 1];
            v[0] = a.x; v[1] = a.y; v[2] = a.z; v[3] = a.w;
            v[4] = bq.x; v[5] = bq.y; v[6] = bq.z; v[7] = bq.w;
        }
#pragma unroll
        for (int p = 0; p < 8; ++p) mx = fmaxf(mx, v[p]);
    }
    mx = wave_max(mx);
    if (!lane) sm[wid] = mx;
    __syncthreads();
    mx = fmaxf(fmaxf(sm[0], sm[1]), fmaxf(sm[2], sm[3]));
    float se = 0.f;
    for (int j = tid; j < V_ / 8; j += 256) {
        float v[8];
        if (isbf) {
            uint4 u = ((const uint4*)lrh)[j];
            uint_t w[4] = {u.x, u.y, u.z, u.w};
#pragma unroll
            for (int p = 0; p < 4; ++p) {
                v[p * 2] = b2f((ushort_t)(w[p] & 0xffff));
                v[p * 2 + 1] = b2f((ushort_t)(w[p] >> 16));
            }
        } else {
            float4 a = ((const float4*)lrf)[j * 2];
            float4 bq = ((const float4*)lrf)[j * 2 + 1];
            v[0] = a.x; v[1] = a.y; v[2] = a.z; v[3] = a.w;
            v[4] = bq.x; v[5] = bq.y; v[6] = bq.z; v[7] = bq.w;
        }
#pragma unroll
        for (int p = 0; p < 8; ++p) se += __expf(v[p] - mx);
    }
    se = wave_sum(se);
    if (!lane) ss[wid] = se;
    __syncthreads();
    if (tid == 0) {
        se = ss[0] + ss[1] + ss[2] + ss[3];
        int tv = tg[t];
        float lv = isbf ? b2f(lrh[tv]) : lrf[tv];
        float nll = mx + __logf(se) - lv;
        rowacc[t] = (tv != 0) ? nll : 0.f;
        rowacc[T_ + t] = (tv != 0) ? 1.f : 0.f;
    }
}

__global__ __launch_bounds__(256) void loss_final(
    const float* __restrict__ rowacc, void* __restrict__ out,
    const int* __restrict__ flagp) {
    const int isbf = *flagp;
    int tid = threadIdx.x;
    int lane = tid & 63, wid = tid >> 6;
    float s = 0.f, c = 0.f;
    for (int i = tid; i < T_; i += 256) { s += rowacc[i]; c += rowacc[T_ + i]; }
    __shared__ float sa[4], sb[4];
    s = wave_sum(s); c = wave_sum(c);
    if (!lane) { sa[wid] = s; sb[wid] = c; }
    __syncthreads();
    if (tid == 0) {
        float S = sa[0] + sa[1] + sa[2] + sa[3];
        float C = sb[0] + sb[1] + sb[2] + sb[3];
        float loss = S / fmaxf(C, 1.f);
        size_t o = (size_t)T_ * V_;
        if (isbf) ((ushort_t*)out)[o] = f2b(loss);
        else ((float*)out)[o] = loss;
    }
}

extern "C" void kernel_launch(void* const* d_in, const int* in_sizes, int n_in,
                              void* d_out, int out_size, void* d_ws,
                              size_t ws_size, hipStream_t stream) {
    const int* x = (const int*)d_in[0];
    const int* targets = (const int*)d_in[1];
    const void* tok_emb = d_in[2];
    const void* pos_emb = d_in[3];
    const void* Wqkv = d_in[4];
    const void* Wo = d_in[5];
    const void* ln1_g = d_in[6];
    const void* ln1_b = d_in[7];
    const void* ln2_g = d_in[8];
    const void* ln2_b = d_in[9];
    const void* W1 = d_in[10];
    const void* b1 = d_in[11];
    const void* W2 = d_in[12];
    const void* b2 = d_in[13];
    const void* lnf_g = d_in[14];
    const void* lnf_b = d_in[15];

    char* ws = (char*)d_ws;
    float* h = (float*)ws;                    // 6.29 MB
    ushort_t* hn = (ushort_t*)(ws + 6291456); // 3.15 MB
    ushort_t* qkvb = (ushort_t*)(ws + 9437184);  // 9.44 MB
    ushort_t* ctxb = (ushort_t*)(ws + 18874368); // 3.15 MB
    ushort_t* ff1 = qkvb;                     // alias, disjoint lifetime
    float* rowacc = (float*)(ws + 22020096);  // 16 KB
    int* d_flag = (int*)(ws + 22036480);

    sniff_kernel<<<1, 64, 0, stream>>>(pos_emb, d_flag);
    embed_kernel<<<T_, 256, 0, stream>>>(x, tok_emb, pos_emb, h, d_flag);

    for (int l = 0; l < L_; ++l) {
        size_t oln = (size_t)l * D_;
        ln_kernel<<<T_, 256, 0, stream>>>(h, ln1_g, oln, ln1_b, oln, hn, d_flag);
        gemm_bt<0><<<dim3(3 * D_ / 128, T_ / 128), 256, 0, stream>>>(
            hn, Wqkv, (size_t)l * 3 * D_ * D_, nullptr, 0, qkvb, nullptr,
            T_, 3 * D_, D_, d_flag);
        attn_mfma<<<dim3(T_ / 64, H_), 256, 0, stream>>>(qkvb, ctxb);
        gemm_bt<2><<<dim3(D_ / 128, T_ / 128), 256, 0, stream>>>(
            ctxb, Wo, (size_t)l * D_ * D_, nullptr, 0, nullptr, h,
            T_, D_, D_, d_flag);
        ln_kernel<<<T_, 256, 0, stream>>>(h, ln2_g, oln, ln2_b, oln, hn, d_flag);
        gemm_bt<1><<<dim3(F_ / 128, T_ / 128), 256, 0, stream>>>(
            hn, W1, (size_t)l * F_ * D_, b1, (size_t)l * F_, ff1, nullptr,
            T_, F_, D_, d_flag);
        gemm_bt<3><<<dim3(D_ / 128, T_ / 128), 256, 0, stream>>>(
            ff1, W2, (size_t)l * D_ * F_, b2, (size_t)l * D_, nullptr, h,
            T_, D_, F_, d_flag);
    }

    ln_kernel<<<T_, 256, 0, stream>>>(h, lnf_g, 0, lnf_b, 0, hn, d_flag);
    gemm_bt<4><<<dim3(V_ / 128, T_ / 128), 256, 0, stream>>>(
        hn, tok_emb, 0, nullptr, 0, (ushort_t*)d_out, nullptr,
        T_, V_, D_, d_flag);
    loss_rows<<<T_, 256, 0, stream>>>(d_out, targets, rowacc, d_flag);
    loss_final<<<1, 256, 0, stream>>>(rowacc, d_out, d_flag);
}

// Round 3
// 2864.771 us; speedup vs baseline: 4.0957x; 1.0037x over previous
//
#include <hip/hip_runtime.h>

// GPT forward on MI355X. R6: logits GEMM was HBM-bound (1.065GB moved at
// 3.76TB/s = exactly its 284us) with 7.8x B over-fetch from n-fastest block
// order -> swap grid for EPI4 (m-fastest, B-tile reuse in L2). Also kill the
// 8-way LDS bank conflict (SQ_LDS_BANK_CONFLICT=1.23e7) in all GEMMs via
// XOR swizzle byte^=(row&7)<<4 on staging writes + fragment reads.
// Internal format: fp32 residual h, bf16 MFMA operands. d_out dtype per flag.

typedef unsigned short ushort_t;
typedef unsigned int uint_t;
typedef __bf16 bf16x8 __attribute__((ext_vector_type(8)));
typedef float floatx4 __attribute__((ext_vector_type(4)));

#define D_ 768
#define T_ 2048
#define H_ 12
#define L_ 6
#define F_ 3072
#define V_ 32000

__device__ __forceinline__ float b2f(ushort_t u) {
    union { uint_t i; float f; } v; v.i = ((uint_t)u) << 16; return v.f;
}
__device__ __forceinline__ ushort_t f2b(float f) {
    uint_t x = __builtin_bit_cast(uint_t, f);
    uint_t r = (x + 0x7fffu + ((x >> 16) & 1u)) >> 16;
    return (ushort_t)r;
}
__device__ __forceinline__ float ldf(const void* p, size_t idx, int isbf) {
    return isbf ? b2f(((const ushort_t*)p)[idx]) : ((const float*)p)[idx];
}
__device__ __forceinline__ float wave_sum(float v) {
    for (int o = 32; o; o >>= 1) v += __shfl_xor(v, o);
    return v;
}
__device__ __forceinline__ float wave_max(float v) {
    for (int o = 32; o; o >>= 1) v = fmaxf(v, __shfl_xor(v, o));
    return v;
}

__global__ void sniff_kernel(const void* __restrict__ pos, int* __restrict__ flag) {
    if (threadIdx.x == 0 && blockIdx.x == 0) {
        const uint_t* w = (const uint_t*)pos;
        int c = 0;
        for (int i = 0; i < 64; ++i) {
            uint_t lo = w[i] & 0xffffu;
            int e = (int)((lo >> 7) & 0xff);
            if (e >= 110 && e < 127) ++c;
        }
        *flag = (c >= 32) ? 1 : 0;  // 1 = bf16 storage
    }
}

__global__ __launch_bounds__(256) void embed_kernel(
    const int* __restrict__ x, const void* __restrict__ tok,
    const void* __restrict__ pos, float* __restrict__ h,
    const int* __restrict__ flagp) {
    const int isbf = *flagp;
    int t = blockIdx.x, tid = threadIdx.x;
    int id = x[t];
    float* hr = h + (size_t)t * D_;
#pragma unroll
    for (int e = 0; e < 3; ++e) {
        int d = tid + e * 256;
        hr[d] = ldf(tok, (size_t)id * D_ + d, isbf) +
                ldf(pos, (size_t)t * D_ + d, isbf);
    }
}

__global__ __launch_bounds__(256) void ln_kernel(
    const float* __restrict__ x, const void* __restrict__ g, size_t go,
    const void* __restrict__ b, size_t bo, ushort_t* __restrict__ out,
    const int* __restrict__ flagp) {
    const int isbf = *flagp;
    int row = blockIdx.x, tid = threadIdx.x;
    int lane = tid & 63, wid = tid >> 6;
    const float* xr = x + (size_t)row * D_;
    float v0 = xr[tid], v1 = xr[tid + 256], v2 = xr[tid + 512];
    __shared__ float s1[4], s2[4];
    float s = wave_sum(v0 + v1 + v2);
    if (!lane) s1[wid] = s;
    __syncthreads();
    float mean = (s1[0] + s1[1] + s1[2] + s1[3]) * (1.f / 768.f);
    float d0 = v0 - mean, d1 = v1 - mean, d2 = v2 - mean;
    float q = wave_sum(d0 * d0 + d1 * d1 + d2 * d2);
    if (!lane) s2[wid] = q;
    __syncthreads();
    float var = (s2[0] + s2[1] + s2[2] + s2[3]) * (1.f / 768.f);
    float rstd = rsqrtf(var + 1e-5f);
    ushort_t* orow = out + (size_t)row * D_;
    orow[tid] = f2b(d0 * rstd * ldf(g, go + tid, isbf) + ldf(b, bo + tid, isbf));
    orow[tid + 256] = f2b(d1 * rstd * ldf(g, go + tid + 256, isbf) + ldf(b, bo + tid + 256, isbf));
    orow[tid + 512] = f2b(d2 * rstd * ldf(g, go + tid + 512, isbf) + ldf(b, bo + tid + 512, isbf));
}

// C[M,N] = A[M,K] * B[N,K]^T.  A: internal bf16. B/bias: flag dtype.
// EPI 0: bf16 store  1: +bias,GELU,bf16 store  2: resid+=  3: resid+=+bias
// EPI 4: store to d_out (dtype per flag); EPI4 grid is (M-blocks, N-blocks)
// (m-fastest) so the 16 blocks sharing a B-tile are dispatch-adjacent.
// LDS swizzle: byte ^= (row&7)<<4 on writes and reads (2 lanes/bank-quad
// per 16-lane phase = conflict-free).
template <int EPI>
__global__ __launch_bounds__(256) void gemm_bt(
    const ushort_t* __restrict__ A, const void* __restrict__ B, size_t Bo,
    const void* __restrict__ bias, size_t biaso, ushort_t* __restrict__ obf,
    float* __restrict__ resid, int M, int N, int K,
    const int* __restrict__ flagp) {
    const int isbf = *flagp;
    __shared__ ushort_t lds[8192];
    const int tid = threadIdx.x;
    const int lane = tid & 63;
    const int wid = tid >> 6;
    const int wm = wid >> 1, wn = wid & 1;
    const int m0 = (EPI == 4 ? (int)blockIdx.x : (int)blockIdx.y) * 128;
    const int n0 = (EPI == 4 ? (int)blockIdx.y : (int)blockIdx.x) * 128;
    const int lm = lane & 15, lq = lane >> 4;

    floatx4 acc[4][4] = {};

    const int arow = tid >> 2, aseg = tid & 3;
    // swizzled LDS ushort index for staging row `arow`, 16B-seg `aseg`
    const int sidx = (((arow * 64) + (aseg << 4)) ^ ((arow & 7) << 4)) >> 1;
    const ushort_t* gA = A + (size_t)(m0 + arow) * K + aseg * 8;
    const size_t bofs = Bo + (size_t)(n0 + arow) * K + aseg * 8;
    const ushort_t* gBh = (const ushort_t*)B + bofs;
    const float* gBf = (const float*)B + bofs;
    ushort_t* sA = lds;
    ushort_t* sB = lds + 4096;

    for (int k0 = 0; k0 < K; k0 += 32) {
        *(uint4*)(sA + sidx) = *(const uint4*)(gA + k0);
        *(uint4*)(sA + 2048 + sidx) = *(const uint4*)(gA + (size_t)64 * K + k0);
        if (isbf) {
            *(uint4*)(sB + sidx) = *(const uint4*)(gBh + k0);
            *(uint4*)(sB + 2048 + sidx) = *(const uint4*)(gBh + (size_t)64 * K + k0);
        } else {
            union { ushort_t u[8]; uint4 v; } p0, p1;
            float4 x0 = *(const float4*)(gBf + k0);
            float4 x1 = *(const float4*)(gBf + k0 + 4);
            float4 y0 = *(const float4*)(gBf + (size_t)64 * K + k0);
            float4 y1 = *(const float4*)(gBf + (size_t)64 * K + k0 + 4);
            p0.u[0] = f2b(x0.x); p0.u[1] = f2b(x0.y); p0.u[2] = f2b(x0.z); p0.u[3] = f2b(x0.w);
            p0.u[4] = f2b(x1.x); p0.u[5] = f2b(x1.y); p0.u[6] = f2b(x1.z); p0.u[7] = f2b(x1.w);
            p1.u[0] = f2b(y0.x); p1.u[1] = f2b(y0.y); p1.u[2] = f2b(y0.z); p1.u[3] = f2b(y0.w);
            p1.u[4] = f2b(y1.x); p1.u[5] = f2b(y1.y); p1.u[6] = f2b(y1.z); p1.u[7] = f2b(y1.w);
            *(uint4*)(sB + sidx) = p0.v;
            *(uint4*)(sB + 2048 + sidx) = p1.v;
        }
        __syncthreads();
        bf16x8 af[4], bfr[4];
#pragma unroll
        for (int f = 0; f < 4; ++f) {
            const int ar = wm * 64 + f * 16 + lm;
            const int br = wn * 64 + f * 16 + lm;
            af[f] = *(const bf16x8*)(sA + ((((ar * 64) + (lq << 4)) ^ ((ar & 7) << 4)) >> 1));
            bfr[f] = *(const bf16x8*)(sB + ((((br * 64) + (lq << 4)) ^ ((br & 7) << 4)) >> 1));
        }
#pragma unroll
        for (int i = 0; i < 4; ++i)
#pragma unroll
            for (int j = 0; j < 4; ++j)
                acc[i][j] = __builtin_amdgcn_mfma_f32_16x16x32_bf16(
                    af[i], bfr[j], acc[i][j], 0, 0, 0);
        __syncthreads();
    }

#pragma unroll
    for (int i = 0; i < 4; ++i) {
#pragma unroll
        for (int j = 0; j < 4; ++j) {
#pragma unroll
            for (int r = 0; r < 4; ++r) {
                int row = m0 + wm * 64 + i * 16 + lq * 4 + r;
                int col = n0 + wn * 64 + j * 16 + lm;
                float c = acc[i][j][r];
                if (EPI == 1 || EPI == 3) c += ldf(bias, biaso + col, isbf);
                if (EPI == 1) c = 0.5f * c * (1.f + erff(c * 0.70710678118f));
                size_t idx = (size_t)row * N + col;
                if (EPI == 0 || EPI == 1) {
                    obf[idx] = f2b(c);
                } else if (EPI == 4) {
                    if (isbf) obf[idx] = f2b(c);
                    else ((float*)obf)[idx] = c;
                } else {
                    resid[idx] += c;
                }
            }
        }
    }
}

// MFMA flash attention. Grid (T/64, H), 256 threads = 4 waves.
// Block handles 64 query rows of one head; wave w owns rows w*16..w*16+15.
// qkv layout: [T][3D], Q at h*64, K at D+h*64, V at 2D+h*64 (bf16).
__global__ __launch_bounds__(256) void attn_mfma(
    const ushort_t* __restrict__ qkv, ushort_t* __restrict__ ctx) {
    // K tile row-major [k][d], stride 72 (+8 pad -> 2-way bank = free on b128 reads)
    __shared__ __attribute__((aligned(16))) ushort_t sK[64 * 72];
    // V^T tile [d][k], stride 72
    __shared__ __attribute__((aligned(16))) ushort_t sVT[64 * 72];
    // P scratch, 16 rows x 72 per wave
    __shared__ __attribute__((aligned(16))) ushort_t sP[64 * 72];

    const int tid = threadIdx.x;
    const int lane = tid & 63;
    const int w = tid >> 6;
    const int lm = lane & 15, lq = lane >> 4;
    const int qt = (int)gridDim.x - 1 - (int)blockIdx.x;  // heavy tiles first
    const int q0 = qt * 64;
    const int h = blockIdx.y;

    // Q fragments (A-operand), pre-scaled by 1/sqrt(64)=0.125 (exact in bf16)
    bf16x8 qf[2];
    {
        const int qrow = q0 + w * 16 + lm;
        const ushort_t* src = qkv + (size_t)qrow * (3 * D_) + h * 64 + lq * 8;
#pragma unroll
        for (int kk = 0; kk < 2; ++kk) {
            union { ushort_t u[8]; uint4 v; bf16x8 b; } tmp;
            tmp.v = *(const uint4*)(src + kk * 32);
#pragma unroll
            for (int e = 0; e < 8; ++e) tmp.u[e] = f2b(b2f(tmp.u[e]) * 0.125f);
            qf[kk] = tmp.b;
        }
    }

    floatx4 acc_o[4] = {};
    float m[4], l[4];
#pragma unroll
    for (int r = 0; r < 4; ++r) { m[r] = -1e30f; l[r] = 0.f; }

    const int krow_s = tid >> 3;  // 0..31
    const int seg = tid & 7;
    ushort_t* pw = sP + w * (16 * 72);

    for (int j0 = 0; j0 <= q0; j0 += 64) {
        // --- stage K tile and V^T tile (reg-staged, all 256 threads) ---
#pragma unroll
        for (int p = 0; p < 2; ++p) {
            const int kr = p * 32 + krow_s;
            const size_t rb = (size_t)(j0 + kr) * (3 * D_) + h * 64 + seg * 8;
            *(uint4*)(sK + kr * 72 + seg * 8) = *(const uint4*)(qkv + rb + D_);
            union { ushort_t u[8]; uint4 v; } tv;
            tv.v = *(const uint4*)(qkv + rb + 2 * D_);
#pragma unroll
            for (int e = 0; e < 8; ++e) sVT[(seg * 8 + e) * 72 + kr] = tv.u[e];
        }
        __syncthreads();

        // --- S = Q K^T (16x64 per wave) ---
        floatx4 sa[4] = {};
#pragma unroll
        for (int nf = 0; nf < 4; ++nf) {
#pragma unroll
            for (int kk = 0; kk < 2; ++kk) {
                bf16x8 kf = *(const bf16x8*)(sK + (nf * 16 + lm) * 72 + kk * 32 + lq * 8);
                sa[nf] = __builtin_amdgcn_mfma_f32_16x16x32_bf16(qf[kk], kf, sa[nf], 0, 0, 0);
            }
        }
        if (j0 == q0) {  // diagonal tile: causal mask (uniform branch)
#pragma unroll
            for (int nf = 0; nf < 4; ++nf)
#pragma unroll
                for (int r = 0; r < 4; ++r)
                    if (j0 + nf * 16 + lm > q0 + w * 16 + lq * 4 + r) sa[nf][r] = -1e30f;
        }

        // --- online softmax: reduce over k (16-lane group, all lanes active) ---
        float rmax[4];
#pragma unroll
        for (int r = 0; r < 4; ++r)
            rmax[r] = fmaxf(fmaxf(sa[0][r], sa[1][r]), fmaxf(sa[2][r], sa[3][r]));
#pragma unroll
        for (int r = 0; r < 4; ++r) {
            rmax[r] = fmaxf(rmax[r], __shfl_xor(rmax[r], 1));
            rmax[r] = fmaxf(rmax[r], __shfl_xor(rmax[r], 2));
            rmax[r] = fmaxf(rmax[r], __shfl_xor(rmax[r], 4));
            rmax[r] = fmaxf(rmax[r], __shfl_xor(rmax[r], 8));
        }
        float alpha[4], rsum[4];
#pragma unroll
        for (int r = 0; r < 4; ++r) {
            float mn = fmaxf(m[r], rmax[r]);
            alpha[r] = __expf(m[r] - mn);
            m[r] = mn;
            rsum[r] = 0.f;
        }
#pragma unroll
        for (int nf = 0; nf < 4; ++nf)
#pragma unroll
            for (int r = 0; r < 4; ++r) {
                float pe = __expf(sa[nf][r] - m[r]);
                rsum[r] += pe;
                pw[(lq * 4 + r) * 72 + nf * 16 + lm] = f2b(pe);
            }
#pragma unroll
        for (int r = 0; r < 4; ++r) {
            rsum[r] += __shfl_xor(rsum[r], 1);
            rsum[r] += __shfl_xor(rsum[r], 2);
            rsum[r] += __shfl_xor(rsum[r], 4);
            rsum[r] += __shfl_xor(rsum[r], 8);
            l[r] = l[r] * alpha[r] + rsum[r];
        }
#pragma unroll
        for (int nf = 0; nf < 4; ++nf)
#pragma unroll
            for (int r = 0; r < 4; ++r) acc_o[nf][r] *= alpha[r];

        // --- O += P V (P re-fragmented via per-wave LDS patch) ---
        bf16x8 pa[2];
#pragma unroll
        for (int kk = 0; kk < 2; ++kk)
            pa[kk] = *(const bf16x8*)(pw + lm * 72 + kk * 32 + lq * 8);
#pragma unroll
        for (int nf = 0; nf < 4; ++nf) {
#pragma unroll
            for (int kk = 0; kk < 2; ++kk) {
                bf16x8 vf = *(const bf16x8*)(sVT + (nf * 16 + lm) * 72 + kk * 32 + lq * 8);
                acc_o[nf] = __builtin_amdgcn_mfma_f32_16x16x32_bf16(pa[kk], vf, acc_o[nf], 0, 0, 0);
            }
        }
        __syncthreads();  // protect sK/sVT before next tile's staging
    }

    float inv[4];
#pragma unroll
    for (int r = 0; r < 4; ++r) inv[r] = 1.f / fmaxf(l[r], 1e-30f);
#pragma unroll
    for (int nf = 0; nf < 4; ++nf)
#pragma unroll
        for (int r = 0; r < 4; ++r) {
            int q = q0 + w * 16 + lq * 4 + r;
            ctx[(size_t)q * D_ + h * 64 + nf * 16 + lm] = f2b(acc_o[nf][r] * inv[r]);
        }
}

__global__ __launch_bounds__(256) void loss_rows(
    const void* __restrict__ logits, const int* __restrict__ tg,
    float* __restrict__ rowacc, const int* __restrict__ flagp) {
    const int isbf = *flagp;
    int t = blockIdx.x, tid = threadIdx.x;
    int lane = tid & 63, wid = tid >> 6;
    const ushort_t* lrh = (const ushort_t*)logits + (size_t)t * V_;
    const float* lrf = (const float*)logits + (size_t)t * V_;
    __shared__ float sm[4], ss[4];
    float mx = -1e30f;
    for (int j = tid; j < V_ / 8; j += 256) {
        float v[8];
        if (isbf) {
            uint4 u = ((const uint4*)lrh)[j];
            uint_t w[4] = {u.x, u.y, u.z, u.w};
#pragma unroll
            for (int p = 0; p < 4; ++p) {
                v[p * 2] = b2f((ushort_t)(w[p] & 0xffff));
                v[p * 2 + 1] = b2f((ushort_t)(w[p] >> 16));
            }
        } else {
            float4 a = ((const float4*)lrf)[j * 2];
            float4 bq = ((const float4*)lrf)[j * 2 + 1];
            v[0] = a.x; v[1] = a.y; v[2] = a.z; v[3] = a.w;
            v[4] = bq.x; v[5] = bq.y; v[6] = bq.z; v[7] = bq.w;
        }
#pragma unroll
        for (int p = 0; p < 8; ++p) mx = fmaxf(mx, v[p]);
    }
    mx = wave_max(mx);
    if (!lane) sm[wid] = mx;
    __syncthreads();
    mx = fmaxf(fmaxf(sm[0], sm[1]), fmaxf(sm[2], sm[3]));
    float se = 0.f;
    for (int j = tid; j < V_ / 8; j += 256) {
        float v[8];
        if (isbf) {
            uint4 u = ((const uint4*)lrh)[j];
            uint_t w[4] = {u.x, u.y, u.z, u.w};
#pragma unroll
            for (int p = 0; p < 4; ++p) {
                v[p * 2] = b2f((ushort_t)(w[p] & 0xffff));
                v[p * 2 + 1] = b2f((ushort_t)(w[p] >> 16));
            }
        } else {
            float4 a = ((const float4*)lrf)[j * 2];
            float4 bq = ((const float4*)lrf)[j * 2 + 1];
            v[0] = a.x; v[1] = a.y; v[2] = a.z; v[3] = a.w;
            v[4] = bq.x; v[5] = bq.y; v[6] = bq.z; v[7] = bq.w;
        }
#pragma unroll
        for (int p = 0; p < 8; ++p) se += __expf(v[p] - mx);
    }
    se = wave_sum(se);
    if (!lane) ss[wid] = se;
    __syncthreads();
    if (tid == 0) {
        se = ss[0] + ss[1] + ss[2] + ss[3];
        int tv = tg[t];
        float lv = isbf ? b2f(lrh[tv]) : lrf[tv];
        float nll = mx + __logf(se) - lv;
        rowacc[t] = (tv != 0) ? nll : 0.f;
        rowacc[T_ + t] = (tv != 0) ? 1.f : 0.f;
    }
}

__global__ __launch_bounds__(256) void loss_final(
    const float* __restrict__ rowacc, void* __restrict__ out,
    const int* __restrict__ flagp) {
    const int isbf = *flagp;
    int tid = threadIdx.x;
    int lane = tid & 63, wid = tid >> 6;
    float s = 0.f, c = 0.f;
    for (int i = tid; i < T_; i += 256) { s += rowacc[i]; c += rowacc[T_ + i]; }
    __shared__ float sa[4], sb[4];
    s = wave_sum(s); c = wave_sum(c);
    if (!lane) { sa[wid] = s; sb[wid] = c; }
    __syncthreads();
    if (tid == 0) {
        float S = sa[0] + sa[1] + sa[2] + sa[3];
        float C = sb[0] + sb[1] + sb[2] + sb[3];
        float loss = S / fmaxf(C, 1.f);
        size_t o = (size_t)T_ * V_;
        if (isbf) ((ushort_t*)out)[o] = f2b(loss);
        else ((float*)out)[o] = loss;
    }
}

extern "C" void kernel_launch(void* const* d_in, const int* in_sizes, int n_in,
                              void* d_out, int out_size, void* d_ws,
                              size_t ws_size, hipStream_t stream) {
    const int* x = (const int*)d_in[0];
    const int* targets = (const int*)d_in[1];
    const void* tok_emb = d_in[2];
    const void* pos_emb = d_in[3];
    const void* Wqkv = d_in[4];
    const void* Wo = d_in[5];
    const void* ln1_g = d_in[6];
    const void* ln1_b = d_in[7];
    const void* ln2_g = d_in[8];
    const void* ln2_b = d_in[9];
    const void* W1 = d_in[10];
    const void* b1 = d_in[11];
    const void* W2 = d_in[12];
    const void* b2 = d_in[13];
    const void* lnf_g = d_in[14];
    const void* lnf_b = d_in[15];

    char* ws = (char*)d_ws;
    float* h = (float*)ws;                    // 6.29 MB
    ushort_t* hn = (ushort_t*)(ws + 6291456); // 3.15 MB
    ushort_t* qkvb = (ushort_t*)(ws + 9437184);  // 9.44 MB
    ushort_t* ctxb = (ushort_t*)(ws + 18874368); // 3.15 MB
    ushort_t* ff1 = qkvb;                     // alias, disjoint lifetime
    float* rowacc = (float*)(ws + 22020096);  // 16 KB
    int* d_flag = (int*)(ws + 22036480);

    sniff_kernel<<<1, 64, 0, stream>>>(pos_emb, d_flag);
    embed_kernel<<<T_, 256, 0, stream>>>(x, tok_emb, pos_emb, h, d_flag);

    for (int l = 0; l < L_; ++l) {
        size_t oln = (size_t)l * D_;
        ln_kernel<<<T_, 256, 0, stream>>>(h, ln1_g, oln, ln1_b, oln, hn, d_flag);
        gemm_bt<0><<<dim3(3 * D_ / 128, T_ / 128), 256, 0, stream>>>(
            hn, Wqkv, (size_t)l * 3 * D_ * D_, nullptr, 0, qkvb, nullptr,
            T_, 3 * D_, D_, d_flag);
        attn_mfma<<<dim3(T_ / 64, H_), 256, 0, stream>>>(qkvb, ctxb);
        gemm_bt<2><<<dim3(D_ / 128, T_ / 128), 256, 0, stream>>>(
            ctxb, Wo, (size_t)l * D_ * D_, nullptr, 0, nullptr, h,
            T_, D_, D_, d_flag);
        ln_kernel<<<T_, 256, 0, stream>>>(h, ln2_g, oln, ln2_b, oln, hn, d_flag);
        gemm_bt<1><<<dim3(F_ / 128, T_ / 128), 256, 0, stream>>>(
            hn, W1, (size_t)l * F_ * D_, b1, (size_t)l * F_, ff1, nullptr,
            T_, F_, D_, d_flag);
        gemm_bt<3><<<dim3(D_ / 128, T_ / 128), 256, 0, stream>>>(
            ff1, W2, (size_t)l * D_ * F_, b2, (size_t)l * D_, nullptr, h,
            T_, D_, F_, d_flag);
    }

    ln_kernel<<<T_, 256, 0, stream>>>(h, lnf_g, 0, lnf_b, 0, hn, d_flag);
    // EPI4: grid (M-blocks, N-blocks) — m-fastest for B-tile L2 reuse
    gemm_bt<4><<<dim3(T_ / 128, V_ / 128), 256, 0, stream>>>(
        hn, tok_emb, 0, nullptr, 0, (ushort_t*)d_out, nullptr,
        T_, V_, D_, d_flag);
    loss_rows<<<T_, 256, 0, stream>>>(d_out, targets, rowacc, d_flag);
    loss_final<<<1, 256, 0, stream>>>(rowacc, d_out, d_flag);
}

// Round 4
// 2756.399 us; speedup vs baseline: 4.2568x; 1.0393x over previous
//
#include <hip/hip_runtime.h>

// GPT forward on MI355X. R7:
//  (1) attn (184us/layer, latency-exposed lockstep staging) -> double-buffered
//      KV with issue-early reg prefetch, 1 barrier/tile, V^T staged as b32
//      row-pairs with XOR slot swizzle (2-way banks instead of 8-way b16).
//  (2) logits gemm: XCD-exclusive n-columns (all 16 m-blocks of an n-column
//      on one XCD's L2) -> B fetched ~1x instead of 4x.
//  (3) loss_rows: single-pass online LSE (halves 524MB logits re-read).
// Internal format: fp32 residual h, bf16 MFMA operands. d_out dtype per flag.

typedef unsigned short ushort_t;
typedef unsigned int uint_t;
typedef __bf16 bf16x8 __attribute__((ext_vector_type(8)));
typedef float floatx4 __attribute__((ext_vector_type(4)));

#define D_ 768
#define T_ 2048
#define H_ 12
#define L_ 6
#define F_ 3072
#define V_ 32000

__device__ __forceinline__ float b2f(ushort_t u) {
    union { uint_t i; float f; } v; v.i = ((uint_t)u) << 16; return v.f;
}
__device__ __forceinline__ ushort_t f2b(float f) {
    uint_t x = __builtin_bit_cast(uint_t, f);
    uint_t r = (x + 0x7fffu + ((x >> 16) & 1u)) >> 16;
    return (ushort_t)r;
}
__device__ __forceinline__ float ldf(const void* p, size_t idx, int isbf) {
    return isbf ? b2f(((const ushort_t*)p)[idx]) : ((const float*)p)[idx];
}
__device__ __forceinline__ float wave_sum(float v) {
    for (int o = 32; o; o >>= 1) v += __shfl_xor(v, o);
    return v;
}
__device__ __forceinline__ float wave_max(float v) {
    for (int o = 32; o; o >>= 1) v = fmaxf(v, __shfl_xor(v, o));
    return v;
}

__global__ void sniff_kernel(const void* __restrict__ pos, int* __restrict__ flag) {
    if (threadIdx.x == 0 && blockIdx.x == 0) {
        const uint_t* w = (const uint_t*)pos;
        int c = 0;
        for (int i = 0; i < 64; ++i) {
            uint_t lo = w[i] & 0xffffu;
            int e = (int)((lo >> 7) & 0xff);
            if (e >= 110 && e < 127) ++c;
        }
        *flag = (c >= 32) ? 1 : 0;  // 1 = bf16 storage
    }
}

__global__ __launch_bounds__(256) void embed_kernel(
    const int* __restrict__ x, const void* __restrict__ tok,
    const void* __restrict__ pos, float* __restrict__ h,
    const int* __restrict__ flagp) {
    const int isbf = *flagp;
    int t = blockIdx.x, tid = threadIdx.x;
    int id = x[t];
    float* hr = h + (size_t)t * D_;
#pragma unroll
    for (int e = 0; e < 3; ++e) {
        int d = tid + e * 256;
        hr[d] = ldf(tok, (size_t)id * D_ + d, isbf) +
                ldf(pos, (size_t)t * D_ + d, isbf);
    }
}

__global__ __launch_bounds__(256) void ln_kernel(
    const float* __restrict__ x, const void* __restrict__ g, size_t go,
    const void* __restrict__ b, size_t bo, ushort_t* __restrict__ out,
    const int* __restrict__ flagp) {
    const int isbf = *flagp;
    int row = blockIdx.x, tid = threadIdx.x;
    int lane = tid & 63, wid = tid >> 6;
    const float* xr = x + (size_t)row * D_;
    float v0 = xr[tid], v1 = xr[tid + 256], v2 = xr[tid + 512];
    __shared__ float s1[4], s2[4];
    float s = wave_sum(v0 + v1 + v2);
    if (!lane) s1[wid] = s;
    __syncthreads();
    float mean = (s1[0] + s1[1] + s1[2] + s1[3]) * (1.f / 768.f);
    float d0 = v0 - mean, d1 = v1 - mean, d2 = v2 - mean;
    float q = wave_sum(d0 * d0 + d1 * d1 + d2 * d2);
    if (!lane) s2[wid] = q;
    __syncthreads();
    float var = (s2[0] + s2[1] + s2[2] + s2[3]) * (1.f / 768.f);
    float rstd = rsqrtf(var + 1e-5f);
    ushort_t* orow = out + (size_t)row * D_;
    orow[tid] = f2b(d0 * rstd * ldf(g, go + tid, isbf) + ldf(b, bo + tid, isbf));
    orow[tid + 256] = f2b(d1 * rstd * ldf(g, go + tid + 256, isbf) + ldf(b, bo + tid + 256, isbf));
    orow[tid + 512] = f2b(d2 * rstd * ldf(g, go + tid + 512, isbf) + ldf(b, bo + tid + 512, isbf));
}

// C[M,N] = A[M,K] * B[N,K]^T.  A: internal bf16. B/bias: flag dtype.
// EPI 0: bf16 store  1: +bias,GELU,bf16 store  2: resid+=  3: resid+=+bias
// EPI 4: store to d_out (dtype per flag), grid (16,250), XCD-exclusive
// n-columns: all 16 m-blocks of an n-column sit at dispatch slots with the
// same (slot%8) so they share one XCD's L2 -> B fetched ~once.
template <int EPI>
__global__ __launch_bounds__(256) void gemm_bt(
    const ushort_t* __restrict__ A, const void* __restrict__ B, size_t Bo,
    const void* __restrict__ bias, size_t biaso, ushort_t* __restrict__ obf,
    float* __restrict__ resid, int M, int N, int K,
    const int* __restrict__ flagp) {
    const int isbf = *flagp;
    __shared__ ushort_t lds[8192];
    const int tid = threadIdx.x;
    const int lane = tid & 63;
    const int wid = tid >> 6;
    const int wm = wid >> 1, wn = wid & 1;
    int m0, n0;
    if (EPI == 4) {
        // grid (16, 250): bid linear, x fastest. 4000 blocks.
        int bid = (int)blockIdx.x + 16 * (int)blockIdx.y;
        int mblk, nblk;
        if (bid < 3968) {
            int xcd = bid & 7, j = bid >> 3;
            mblk = j & 15;
            nblk = xcd + 8 * (j >> 4);   // n in [0,248)
        } else {
            int u = bid - 3968;
            nblk = 248 + (u >> 4);
            mblk = u & 15;
        }
        m0 = mblk * 128; n0 = nblk * 128;
    } else {
        m0 = (int)blockIdx.y * 128; n0 = (int)blockIdx.x * 128;
    }
    const int lm = lane & 15, lq = lane >> 4;

    floatx4 acc[4][4] = {};

    const int arow = tid >> 2, aseg = tid & 3;
    // swizzled LDS ushort index for staging row `arow`, 16B-seg `aseg`
    const int sidx = (((arow * 64) + (aseg << 4)) ^ ((arow & 7) << 4)) >> 1;
    const ushort_t* gA = A + (size_t)(m0 + arow) * K + aseg * 8;
    const size_t bofs = Bo + (size_t)(n0 + arow) * K + aseg * 8;
    const ushort_t* gBh = (const ushort_t*)B + bofs;
    const float* gBf = (const float*)B + bofs;
    ushort_t* sA = lds;
    ushort_t* sB = lds + 4096;

    for (int k0 = 0; k0 < K; k0 += 32) {
        *(uint4*)(sA + sidx) = *(const uint4*)(gA + k0);
        *(uint4*)(sA + 2048 + sidx) = *(const uint4*)(gA + (size_t)64 * K + k0);
        if (isbf) {
            *(uint4*)(sB + sidx) = *(const uint4*)(gBh + k0);
            *(uint4*)(sB + 2048 + sidx) = *(const uint4*)(gBh + (size_t)64 * K + k0);
        } else {
            union { ushort_t u[8]; uint4 v; } p0, p1;
            float4 x0 = *(const float4*)(gBf + k0);
            float4 x1 = *(const float4*)(gBf + k0 + 4);
            float4 y0 = *(const float4*)(gBf + (size_t)64 * K + k0);
            float4 y1 = *(const float4*)(gBf + (size_t)64 * K + k0 + 4);
            p0.u[0] = f2b(x0.x); p0.u[1] = f2b(x0.y); p0.u[2] = f2b(x0.z); p0.u[3] = f2b(x0.w);
            p0.u[4] = f2b(x1.x); p0.u[5] = f2b(x1.y); p0.u[6] = f2b(x1.z); p0.u[7] = f2b(x1.w);
            p1.u[0] = f2b(y0.x); p1.u[1] = f2b(y0.y); p1.u[2] = f2b(y0.z); p1.u[3] = f2b(y0.w);
            p1.u[4] = f2b(y1.x); p1.u[5] = f2b(y1.y); p1.u[6] = f2b(y1.z); p1.u[7] = f2b(y1.w);
            *(uint4*)(sB + sidx) = p0.v;
            *(uint4*)(sB + 2048 + sidx) = p1.v;
        }
        __syncthreads();
        bf16x8 af[4], bfr[4];
#pragma unroll
        for (int f = 0; f < 4; ++f) {
            const int ar = wm * 64 + f * 16 + lm;
            const int br = wn * 64 + f * 16 + lm;
            af[f] = *(const bf16x8*)(sA + ((((ar * 64) + (lq << 4)) ^ ((ar & 7) << 4)) >> 1));
            bfr[f] = *(const bf16x8*)(sB + ((((br * 64) + (lq << 4)) ^ ((br & 7) << 4)) >> 1));
        }
#pragma unroll
        for (int i = 0; i < 4; ++i)
#pragma unroll
            for (int j = 0; j < 4; ++j)
                acc[i][j] = __builtin_amdgcn_mfma_f32_16x16x32_bf16(
                    af[i], bfr[j], acc[i][j], 0, 0, 0);
        __syncthreads();
    }

#pragma unroll
    for (int i = 0; i < 4; ++i) {
#pragma unroll
        for (int j = 0; j < 4; ++j) {
#pragma unroll
            for (int r = 0; r < 4; ++r) {
                int row = m0 + wm * 64 + i * 16 + lq * 4 + r;
                int col = n0 + wn * 64 + j * 16 + lm;
                float c = acc[i][j][r];
                if (EPI == 1 || EPI == 3) c += ldf(bias, biaso + col, isbf);
                if (EPI == 1) c = 0.5f * c * (1.f + erff(c * 0.70710678118f));
                size_t idx = (size_t)row * N + col;
                if (EPI == 0 || EPI == 1) {
                    obf[idx] = f2b(c);
                } else if (EPI == 4) {
                    if (isbf) obf[idx] = f2b(c);
                    else ((float*)obf)[idx] = c;
                } else {
                    resid[idx] += c;
                }
            }
        }
    }
}

// MFMA flash attention. Grid (T/64, H), 256 threads = 4 waves.
// Block handles 64 query rows of one head; wave w owns rows w*16..w*16+15.
// R7: double-buffered K/V, issue-early reg prefetch (loads for tile t+1 in
// flight during compute of tile t), 1 barrier/tile. V^T staged as b32
// row-pairs at slot (k2 ^ seg<<2) -> 2 lanes/bank.
__global__ __launch_bounds__(256) void attn_mfma(
    const ushort_t* __restrict__ qkv, ushort_t* __restrict__ ctx) {
    __shared__ __attribute__((aligned(16))) ushort_t sK[2][64 * 72];   // [k][d]
    __shared__ __attribute__((aligned(16))) ushort_t sVT[2][64 * 80];  // [d][k-pairs]
    __shared__ __attribute__((aligned(16))) ushort_t sP[4][16 * 72];   // per-wave

    const int tid = threadIdx.x;
    const int lane = tid & 63;
    const int w = tid >> 6;
    const int lm = lane & 15, lq = lane >> 4;
    const int qt = (int)gridDim.x - 1 - (int)blockIdx.x;  // heavy tiles first
    const int q0 = qt * 64;
    const int h = blockIdx.y;

    // Q fragments (A-operand), pre-scaled by 1/sqrt(64)=0.125 (exact in bf16)
    bf16x8 qf[2];
    {
        const int qrow = q0 + w * 16 + lm;
        const ushort_t* src = qkv + (size_t)qrow * (3 * D_) + h * 64 + lq * 8;
#pragma unroll
        for (int kk = 0; kk < 2; ++kk) {
            union { ushort_t u[8]; uint4 v; bf16x8 b; } tmp;
            tmp.v = *(const uint4*)(src + kk * 32);
#pragma unroll
            for (int e = 0; e < 8; ++e) tmp.u[e] = f2b(b2f(tmp.u[e]) * 0.125f);
            qf[kk] = tmp.b;
        }
    }

    floatx4 acc_o[4] = {};
    float m[4], l[4];
#pragma unroll
    for (int r = 0; r < 4; ++r) { m[r] = -1e30f; l[r] = 0.f; }

    const int k2 = tid >> 3;   // key row-pair index 0..31
    const int seg = tid & 7;   // 16B column segment
    const size_t colo = (size_t)h * 64 + seg * 8;
    const int vslot = 2 * (k2 ^ (seg << 2));  // swizzled pair slot (ushorts)
    ushort_t* pw = sP[w];

    uint4 kreg[2], vreg[2];
    auto issue = [&](int j0) {
        const ushort_t* r0 = qkv + (size_t)(j0 + 2 * k2) * (3 * D_) + colo;
        kreg[0] = *(const uint4*)(r0 + D_);
        vreg[0] = *(const uint4*)(r0 + 2 * D_);
        const ushort_t* r1 = r0 + 3 * D_;
        kreg[1] = *(const uint4*)(r1 + D_);
        vreg[1] = *(const uint4*)(r1 + 2 * D_);
    };
    auto commit = [&](int b) {
        *(uint4*)(&sK[b][(2 * k2) * 72 + seg * 8]) = kreg[0];
        *(uint4*)(&sK[b][(2 * k2 + 1) * 72 + seg * 8]) = kreg[1];
        union { uint4 v; ushort_t u[8]; } v0, v1;
        v0.v = vreg[0]; v1.v = vreg[1];
#pragma unroll
        for (int e = 0; e < 8; ++e) {
            const int d = seg * 8 + e;
            *(uint_t*)(&sVT[b][d * 80 + vslot]) =
                (uint_t)v0.u[e] | ((uint_t)v1.u[e] << 16);
        }
    };

    const int nt = qt;  // tiles t = 0..nt, tile t covers keys [64t, 64t+64)
    issue(0);
    commit(0);
    __syncthreads();

    for (int t = 0; t <= nt; ++t) {
        const int cur = t & 1;
        if (t < nt) issue((t + 1) * 64);  // in flight during compute

        // --- S = Q K^T (16x64 per wave) ---
        floatx4 sa[4] = {};
#pragma unroll
        for (int nf = 0; nf < 4; ++nf) {
#pragma unroll
            for (int kk = 0; kk < 2; ++kk) {
                bf16x8 kf = *(const bf16x8*)(&sK[cur][(nf * 16 + lm) * 72 + kk * 32 + lq * 8]);
                sa[nf] = __builtin_amdgcn_mfma_f32_16x16x32_bf16(qf[kk], kf, sa[nf], 0, 0, 0);
            }
        }
        if (t == nt) {  // diagonal tile: causal mask (uniform branch)
#pragma unroll
            for (int nf = 0; nf < 4; ++nf)
#pragma unroll
                for (int r = 0; r < 4; ++r)
                    if (nf * 16 + lm > w * 16 + lq * 4 + r) sa[nf][r] = -1e30f;
        }

        // --- online softmax (16-lane-group reduce over k, all lanes active) ---
        float rmax[4];
#pragma unroll
        for (int r = 0; r < 4; ++r)
            rmax[r] = fmaxf(fmaxf(sa[0][r], sa[1][r]), fmaxf(sa[2][r], sa[3][r]));
#pragma unroll
        for (int r = 0; r < 4; ++r) {
            rmax[r] = fmaxf(rmax[r], __shfl_xor(rmax[r], 1));
            rmax[r] = fmaxf(rmax[r], __shfl_xor(rmax[r], 2));
            rmax[r] = fmaxf(rmax[r], __shfl_xor(rmax[r], 4));
            rmax[r] = fmaxf(rmax[r], __shfl_xor(rmax[r], 8));
        }
        float alpha[4], rsum[4];
#pragma unroll
        for (int r = 0; r < 4; ++r) {
            float mn = fmaxf(m[r], rmax[r]);
            alpha[r] = __expf(m[r] - mn);
            m[r] = mn;
            rsum[r] = 0.f;
        }
#pragma unroll
        for (int nf = 0; nf < 4; ++nf)
#pragma unroll
            for (int r = 0; r < 4; ++r) {
                float pe = __expf(sa[nf][r] - m[r]);
                rsum[r] += pe;
                pw[(lq * 4 + r) * 72 + nf * 16 + lm] = f2b(pe);
            }
#pragma unroll
        for (int r = 0; r < 4; ++r) {
            rsum[r] += __shfl_xor(rsum[r], 1);
            rsum[r] += __shfl_xor(rsum[r], 2);
            rsum[r] += __shfl_xor(rsum[r], 4);
            rsum[r] += __shfl_xor(rsum[r], 8);
            l[r] = l[r] * alpha[r] + rsum[r];
        }
#pragma unroll
        for (int nf = 0; nf < 4; ++nf)
#pragma unroll
            for (int r = 0; r < 4; ++r) acc_o[nf][r] *= alpha[r];

        // --- O += P V (P re-fragmented via per-wave LDS patch) ---
        bf16x8 pa[2];
#pragma unroll
        for (int kk = 0; kk < 2; ++kk)
            pa[kk] = *(const bf16x8*)(&pw[lm * 72 + kk * 32 + lq * 8]);
#pragma unroll
        for (int nf = 0; nf < 4; ++nf) {
            const int d = nf * 16 + lm;
#pragma unroll
            for (int kk = 0; kk < 2; ++kk) {
                const int p0 = (kk * 16 + lq * 4) ^ (((d >> 3) & 7) << 2);
                bf16x8 vf = *(const bf16x8*)(&sVT[cur][d * 80 + 2 * p0]);
                acc_o[nf] = __builtin_amdgcn_mfma_f32_16x16x32_bf16(pa[kk], vf, acc_o[nf], 0, 0, 0);
            }
        }

        if (t < nt) commit(cur ^ 1);  // write next tile into other buffer
        __syncthreads();
    }

    float inv[4];
#pragma unroll
    for (int r = 0; r < 4; ++r) inv[r] = 1.f / fmaxf(l[r], 1e-30f);
#pragma unroll
    for (int nf = 0; nf < 4; ++nf)
#pragma unroll
        for (int r = 0; r < 4; ++r) {
            int q = q0 + w * 16 + lq * 4 + r;
            ctx[(size_t)q * D_ + h * 64 + nf * 16 + lm] = f2b(acc_o[nf][r] * inv[r]);
        }
}

// single-pass online log-sum-exp per row
__global__ __launch_bounds__(256) void loss_rows(
    const void* __restrict__ logits, const int* __restrict__ tg,
    float* __restrict__ rowacc, const int* __restrict__ flagp) {
    const int isbf = *flagp;
    int t = blockIdx.x, tid = threadIdx.x;
    int lane = tid & 63, wid = tid >> 6;
    const ushort_t* lrh = (const ushort_t*)logits + (size_t)t * V_;
    const float* lrf = (const float*)logits + (size_t)t * V_;
    __shared__ float sm[4], ss[4];
    float mx = -1e30f, se = 0.f;
    for (int j = tid; j < V_ / 8; j += 256) {
        float v[8];
        if (isbf) {
            uint4 u = ((const uint4*)lrh)[j];
            uint_t w[4] = {u.x, u.y, u.z, u.w};
#pragma unroll
            for (int p = 0; p < 4; ++p) {
                v[p * 2] = b2f((ushort_t)(w[p] & 0xffff));
                v[p * 2 + 1] = b2f((ushort_t)(w[p] >> 16));
            }
        } else {
            float4 a = ((const float4*)lrf)[j * 2];
            float4 bq = ((const float4*)lrf)[j * 2 + 1];
            v[0] = a.x; v[1] = a.y; v[2] = a.z; v[3] = a.w;
            v[4] = bq.x; v[5] = bq.y; v[6] = bq.z; v[7] = bq.w;
        }
        float m8 = fmaxf(fmaxf(fmaxf(v[0], v[1]), fmaxf(v[2], v[3])),
                         fmaxf(fmaxf(v[4], v[5]), fmaxf(v[6], v[7])));
        float nm = fmaxf(mx, m8);
        se *= __expf(mx - nm);
#pragma unroll
        for (int p = 0; p < 8; ++p) se += __expf(v[p] - nm);
        mx = nm;
    }
    float M = wave_max(mx);
    se = wave_sum(se * __expf(mx - M));
    if (!lane) { sm[wid] = M; ss[wid] = se; }
    __syncthreads();
    if (tid == 0) {
        float bm = fmaxf(fmaxf(sm[0], sm[1]), fmaxf(sm[2], sm[3]));
        float bs = ss[0] * __expf(sm[0] - bm) + ss[1] * __expf(sm[1] - bm) +
                   ss[2] * __expf(sm[2] - bm) + ss[3] * __expf(sm[3] - bm);
        int tv = tg[t];
        float lv = isbf ? b2f(lrh[tv]) : lrf[tv];
        float nll = bm + __logf(bs) - lv;
        rowacc[t] = (tv != 0) ? nll : 0.f;
        rowacc[T_ + t] = (tv != 0) ? 1.f : 0.f;
    }
}

__global__ __launch_bounds__(256) void loss_final(
    const float* __restrict__ rowacc, void* __restrict__ out,
    const int* __restrict__ flagp) {
    const int isbf = *flagp;
    int tid = threadIdx.x;
    int lane = tid & 63, wid = tid >> 6;
    float s = 0.f, c = 0.f;
    for (int i = tid; i < T_; i += 256) { s += rowacc[i]; c += rowacc[T_ + i]; }
    __shared__ float sa[4], sb[4];
    s = wave_sum(s); c = wave_sum(c);
    if (!lane) { sa[wid] = s; sb[wid] = c; }
    __syncthreads();
    if (tid == 0) {
        float S = sa[0] + sa[1] + sa[2] + sa[3];
        float C = sb[0] + sb[1] + sb[2] + sb[3];
        float loss = S / fmaxf(C, 1.f);
        size_t o = (size_t)T_ * V_;
        if (isbf) ((ushort_t*)out)[o] = f2b(loss);
        else ((float*)out)[o] = loss;
    }
}

extern "C" void kernel_launch(void* const* d_in, const int* in_sizes, int n_in,
                              void* d_out, int out_size, void* d_ws,
                              size_t ws_size, hipStream_t stream) {
    const int* x = (const int*)d_in[0];
    const int* targets = (const int*)d_in[1];
    const void* tok_emb = d_in[2];
    const void* pos_emb = d_in[3];
    const void* Wqkv = d_in[4];
    const void* Wo = d_in[5];
    const void* ln1_g = d_in[6];
    const void* ln1_b = d_in[7];
    const void* ln2_g = d_in[8];
    const void* ln2_b = d_in[9];
    const void* W1 = d_in[10];
    const void* b1 = d_in[11];
    const void* W2 = d_in[12];
    const void* b2 = d_in[13];
    const void* lnf_g = d_in[14];
    const void* lnf_b = d_in[15];

    char* ws = (char*)d_ws;
    float* h = (float*)ws;                    // 6.29 MB
    ushort_t* hn = (ushort_t*)(ws + 6291456); // 3.15 MB
    ushort_t* qkvb = (ushort_t*)(ws + 9437184);  // 9.44 MB
    ushort_t* ctxb = (ushort_t*)(ws + 18874368); // 3.15 MB
    ushort_t* ff1 = qkvb;                     // alias, disjoint lifetime
    float* rowacc = (float*)(ws + 22020096);  // 16 KB
    int* d_flag = (int*)(ws + 22036480);

    sniff_kernel<<<1, 64, 0, stream>>>(pos_emb, d_flag);
    embed_kernel<<<T_, 256, 0, stream>>>(x, tok_emb, pos_emb, h, d_flag);

    for (int l = 0; l < L_; ++l) {
        size_t oln = (size_t)l * D_;
        ln_kernel<<<T_, 256, 0, stream>>>(h, ln1_g, oln, ln1_b, oln, hn, d_flag);
        gemm_bt<0><<<dim3(3 * D_ / 128, T_ / 128), 256, 0, stream>>>(
            hn, Wqkv, (size_t)l * 3 * D_ * D_, nullptr, 0, qkvb, nullptr,
            T_, 3 * D_, D_, d_flag);
        attn_mfma<<<dim3(T_ / 64, H_), 256, 0, stream>>>(qkvb, ctxb);
        gemm_bt<2><<<dim3(D_ / 128, T_ / 128), 256, 0, stream>>>(
            ctxb, Wo, (size_t)l * D_ * D_, nullptr, 0, nullptr, h,
            T_, D_, D_, d_flag);
        ln_kernel<<<T_, 256, 0, stream>>>(h, ln2_g, oln, ln2_b, oln, hn, d_flag);
        gemm_bt<1><<<dim3(F_ / 128, T_ / 128), 256, 0, stream>>>(
            hn, W1, (size_t)l * F_ * D_, b1, (size_t)l * F_, ff1, nullptr,
            T_, F_, D_, d_flag);
        gemm_bt<3><<<dim3(D_ / 128, T_ / 128), 256, 0, stream>>>(
            ff1, W2, (size_t)l * D_ * F_, b2, (size_t)l * D_, nullptr, h,
            T_, D_, F_, d_flag);
    }

    ln_kernel<<<T_, 256, 0, stream>>>(h, lnf_g, 0, lnf_b, 0, hn, d_flag);
    // EPI4: grid (M-blocks, N-blocks) with XCD-aware in-kernel remap
    gemm_bt<4><<<dim3(T_ / 128, V_ / 128), 256, 0, stream>>>(
        hn, tok_emb, 0, nullptr, 0, (ushort_t*)d_out, nullptr,
        T_, V_, D_, d_flag);
    loss_rows<<<T_, 256, 0, stream>>>(d_out, targets, rowacc, d_flag);
    loss_final<<<1, 256, 0, stream>>>(rowacc, d_out, d_flag);
}